// Round 7
// baseline (111.988 us; speedup 1.0000x reference)
//
#include <hip/hip_runtime.h>
#include <math.h>

// Problem dims
#define B_   512
#define F_   1024
#define H1_  512
#define H2_  256
#define OUT_ 128
#define KD_  5
#define NT_  640
#define ZK_  384   // H2_ + OUT_

typedef short bf16x8 __attribute__((ext_vector_type(8)));
typedef float f32x16 __attribute__((ext_vector_type(16)));
typedef float f32x2  __attribute__((ext_vector_type(2)));

#define LOG2E 1.4426950408889634f

__device__ __forceinline__ float lrelu(float v) { return v >= 0.f ? v : 0.2f * v; }

// fp32 -> bf16 round-to-nearest-even
__device__ __forceinline__ unsigned f2bf(float f) {
    unsigned u = __float_as_uint(f);
    return (u + 0x7fffu + ((u >> 16) & 1u)) >> 16;
}
__device__ __forceinline__ unsigned pack2bf(float a, float b) {
    return f2bf(a) | (f2bf(b) << 16);
}

// ---------------------------------------------------------------------------
// MFMA fragment loaders (A/B lane layout: idx = lane&31, k = (lane>>5)*8 + j,
// j = 0..7 contiguous). Verified rounds 3-6 (absmax 5.9e-3).
// ---------------------------------------------------------------------------
__device__ __forceinline__ bf16x8 frag_bf16row(const unsigned short* p, int idx, int ld, int k) {
    return *(const bf16x8*)(p + (size_t)idx * ld + k);
}
__device__ __forceinline__ bf16x8 frag_f32row(const float* p, int idx, int ld, int k) {
    const float4 a = *(const float4*)(p + (size_t)idx * ld + k);
    const float4 b = *(const float4*)(p + (size_t)idx * ld + k + 4);
    union { unsigned u[4]; bf16x8 v; } cv;
    cv.u[0] = pack2bf(a.x, a.y); cv.u[1] = pack2bf(a.z, a.w);
    cv.u[2] = pack2bf(b.x, b.y); cv.u[3] = pack2bf(b.z, b.w);
    return cv.v;
}
// column gather from fp32 [K][ld] matrix: element j = p[(k+j)*ld + idx]
__device__ __forceinline__ bf16x8 frag_f32col(const float* p, int idx, int ld, int k) {
    union { unsigned u[4]; bf16x8 v; } cv;
    #pragma unroll
    for (int jj = 0; jj < 4; ++jj)
        cv.u[jj] = pack2bf(p[(size_t)(k + 2 * jj) * ld + idx],
                           p[(size_t)(k + 2 * jj + 1) * ld + idx]);
    return cv.v;
}
// concat([h2b bf16 (ld 256), obA+obB fp32 (ld 128)]) row, K=384
__device__ __forceinline__ bf16x8 frag_concat(const unsigned short* h2b,
                                              const float* obA, const float* obB,
                                              int idx, int k) {
    if (k < H2_) return frag_bf16row(h2b, idx, H2_, k);
    const float* pa = obA + (size_t)idx * OUT_ + (k - H2_);
    const float* pb = obB + (size_t)idx * OUT_ + (k - H2_);
    union { unsigned u[4]; bf16x8 v; } cv;
    #pragma unroll
    for (int jj = 0; jj < 4; ++jj)
        cv.u[jj] = pack2bf(pa[2 * jj] + pb[2 * jj], pa[2 * jj + 1] + pb[2 * jj + 1]);
    return cv.v;
}

// operand modes
#define M_BF16ROW 0
#define M_F32ROW  1
#define M_F32COL  2

// ---------------------------------------------------------------------------
// Barrier-free MFMA GEMM, one 32x32 tile per block, K split across WAVES
// waves (no barriers/LDS in the K-loop; single LDS reduction + epilogue).
// SCALE: multiply outputs by LOG2E (folds the exp->exp2 conversion of the
// disc stage into the Mt producer: sum|c*mi - c*mj| = c*sum|mi-mj|, c>0).
// ---------------------------------------------------------------------------
template<int WAVES, int KSLICE, int AMODE, int BMODE,
         bool RELU, bool HAS_BIAS, bool BF16_OUT, bool SCALE>
__global__ __launch_bounds__(WAVES * 64)
void gemm_k(const void* __restrict__ Ap, const void* __restrict__ Bp,
            const float* __restrict__ bias, void* __restrict__ Cout,
            int M, int N, int LDA, int LDB)
{
    __shared__ float Red[WAVES * 1024];
    const int tid  = threadIdx.x;
    const int wav  = tid >> 6;
    const int lane = tid & 63;
    const int half = lane >> 5;
    const int mn   = lane & 31;
    const int m0   = blockIdx.y * 32;
    const int n0   = blockIdx.x * 32;

    f32x16 acc;
    #pragma unroll
    for (int i = 0; i < 16; ++i) acc[i] = 0.f;

    #pragma unroll
    for (int s = 0; s < KSLICE / 16; ++s) {
        const int k = wav * KSLICE + 16 * s + 8 * half;
        bf16x8 af, bf;
        if (AMODE == M_BF16ROW)      af = frag_bf16row((const unsigned short*)Ap, m0 + mn, LDA, k);
        else if (AMODE == M_F32ROW)  af = frag_f32row((const float*)Ap, m0 + mn, LDA, k);
        else                         af = frag_f32col((const float*)Ap, m0 + mn, LDA, k);
        if (BMODE == M_BF16ROW)      bf = frag_bf16row((const unsigned short*)Bp, n0 + mn, LDB, k);
        else                         bf = frag_f32col((const float*)Bp, n0 + mn, LDB, k);
        acc = __builtin_amdgcn_mfma_f32_32x32x16_bf16(af, bf, acc, 0, 0, 0);
    }

    // C/D layout (verified): col = lane&31, row = (reg&3) + 8*(reg>>2) + 4*(lane>>5)
    #pragma unroll
    for (int r = 0; r < 16; ++r) {
        const int row = (r & 3) + 8 * (r >> 2) + 4 * half;
        Red[wav * 1024 + row * 32 + mn] = acc[r];
    }
    __syncthreads();

    if (tid < 256) {
        const int e0 = tid * 4, row = e0 >> 5, col = e0 & 31;
        float v[4];
        #pragma unroll
        for (int q = 0; q < 4; ++q) {
            float u = 0.f;
            #pragma unroll
            for (int w = 0; w < WAVES; ++w) u += Red[w * 1024 + e0 + q];
            if (HAS_BIAS) u += bias[n0 + col + q];
            if (RELU) u = lrelu(u);
            if (SCALE) u *= LOG2E;
            v[q] = u;
        }
        if (BF16_OUT) {
            uint2 o;
            o.x = pack2bf(v[0], v[1]); o.y = pack2bf(v[2], v[3]);
            *(uint2*)((unsigned short*)Cout + (size_t)(m0 + row) * N + n0 + col) = o;
        } else {
            *(float4*)((float*)Cout + (size_t)(m0 + row) * N + n0 + col) =
                make_float4(v[0], v[1], v[2], v[3]);
        }
    }
}

// ---------------------------------------------------------------------------
// Minibatch discrimination, packed-fp32 version.
//   Mt: fp32 [640][512], PRE-SCALED by log2(e); row nt = o*5+k.
//   block = (o, j-quarter, i-half): 1024 blocks x 128 threads.
//   obH[ih][j][o] = sum_{i in half} exp2(-L1_scaled) - (self ? 1 : 0)
//   LDS layout [5][256] (Mt-native): an i-pair is one broadcast ds_read_b64;
//   math on f32x2 -> v_pk_sub/v_pk_max (|d| = max(d,-d)) / v_pk_add;
//   exp2 with free neg modifier (log2e folded upstream).
// ---------------------------------------------------------------------------
__global__ __launch_bounds__(128)
void disc_kernel(const float* __restrict__ Mt, float* __restrict__ obH)
{
    const int o  = blockIdx.x >> 3;
    const int jq = (blockIdx.x >> 1) & 3;
    const int ih = blockIdx.x & 1;
    const int t  = threadIdx.x;
    const int j  = jq * 128 + t;
    const int i0 = ih * 256;
    __shared__ float L[KD_ * 256];          // [k][i-half]
    const float* base = Mt + (size_t)o * 5 * 512;
    #pragma unroll
    for (int k = 0; k < KD_; ++k) {
        L[k * 256 + t]       = base[k * 512 + i0 + t];
        L[k * 256 + 128 + t] = base[k * 512 + i0 + t + 128];
    }
    f32x2 mj0, mj1, mj2, mj3, mj4;
    mj0.x = mj0.y = base[0 * 512 + j];
    mj1.x = mj1.y = base[1 * 512 + j];
    mj2.x = mj2.y = base[2 * 512 + j];
    mj3.x = mj3.y = base[3 * 512 + j];
    mj4.x = mj4.y = base[4 * 512 + j];
    __syncthreads();

    float accA = 0.f, accB = 0.f;
    #pragma unroll 4
    for (int i = 0; i < 256; i += 2) {
        const f32x2 a0 = *(const f32x2*)&L[0 * 256 + i];
        const f32x2 a1 = *(const f32x2*)&L[1 * 256 + i];
        const f32x2 a2 = *(const f32x2*)&L[2 * 256 + i];
        const f32x2 a3 = *(const f32x2*)&L[3 * 256 + i];
        const f32x2 a4 = *(const f32x2*)&L[4 * 256 + i];
        const f32x2 d0 = a0 - mj0, d1 = a1 - mj1, d2 = a2 - mj2,
                    d3 = a3 - mj3, d4 = a4 - mj4;
        const f32x2 n = __builtin_elementwise_max(d0, -d0)
                      + __builtin_elementwise_max(d1, -d1)
                      + __builtin_elementwise_max(d2, -d2)
                      + __builtin_elementwise_max(d3, -d3)
                      + __builtin_elementwise_max(d4, -d4);
        accA += __builtin_amdgcn_exp2f(-n.x);
        accB += __builtin_amdgcn_exp2f(-n.y);
    }
    const float self = ((j >> 8) == ih) ? 1.f : 0.f;
    obH[(size_t)ih * B_ * OUT_ + (size_t)j * OUT_ + o] = accA + accB - self;
}

// ---------------------------------------------------------------------------
// Fused GEMM3 + final dot: 16 blocks x 256 threads. Block = 32-row strip.
// Wave w computes col-tile n0 = w*32 over full K=384 (concat A, W3 col
// gather B). Epilogue: bias+lrelu into Red[32][128], then rotated LDS dot
// with W4 -> out.
// ---------------------------------------------------------------------------
__global__ __launch_bounds__(256)
void gemm3_dot(const unsigned short* __restrict__ h2b,
               const float* __restrict__ obA, const float* __restrict__ obB,
               const float* __restrict__ W3, const float* __restrict__ b3,
               const float* __restrict__ W4, const float* __restrict__ b4,
               float* __restrict__ out)
{
    __shared__ float Red[32 * 128];
    const int tid  = threadIdx.x;
    const int w    = tid >> 6;
    const int lane = tid & 63;
    const int half = lane >> 5;
    const int mn   = lane & 31;
    const int m0   = blockIdx.x * 32;
    const int n0   = w * 32;

    f32x16 acc;
    #pragma unroll
    for (int i = 0; i < 16; ++i) acc[i] = 0.f;

    #pragma unroll
    for (int s = 0; s < ZK_ / 16; ++s) {
        const int k = 16 * s + 8 * half;
        const bf16x8 af = frag_concat(h2b, obA, obB, m0 + mn, k);
        const bf16x8 bf = frag_f32col(W3, n0 + mn, OUT_, k);
        acc = __builtin_amdgcn_mfma_f32_32x32x16_bf16(af, bf, acc, 0, 0, 0);
    }

    #pragma unroll
    for (int r = 0; r < 16; ++r) {
        const int row = (r & 3) + 8 * (r >> 2) + 4 * half;
        const int col = n0 + mn;
        Red[row * 128 + col] = lrelu(acc[r] + b3[col]);
    }
    __syncthreads();

    if (tid < 128) {
        const int row = tid >> 2, q = tid & 3;
        float a = 0.f;
        #pragma unroll
        for (int cc0 = 0; cc0 < 32; ++cc0) {
            const int cc = (cc0 + tid) & 31;       // rotation: 2-way LDS aliasing (free)
            a += Red[row * 128 + q * 32 + cc] * W4[q * 32 + cc];
        }
        a += __shfl_down(a, 2, 4);
        a += __shfl_down(a, 1, 4);
        if (q == 0) out[m0 + row] = a + b4[0];
    }
}

extern "C" void kernel_launch(void* const* d_in, const int* in_sizes, int n_in,
                              void* d_out, int out_size, void* d_ws, size_t ws_size,
                              hipStream_t stream) {
    const float* x  = (const float*)d_in[0];   // (512, 1024)
    const float* W1 = (const float*)d_in[1];   // (1024, 512)
    const float* b1 = (const float*)d_in[2];   // (512,)
    const float* W2 = (const float*)d_in[3];   // (512, 256)
    const float* b2 = (const float*)d_in[4];   // (256,)
    const float* T  = (const float*)d_in[5];   // (256, 640) flat
    const float* W3 = (const float*)d_in[6];   // (384, 128)
    const float* b3 = (const float*)d_in[7];   // (128,)
    const float* W4 = (const float*)d_in[8];   // (128, 1)
    const float* b4 = (const float*)d_in[9];   // (1,)
    float* out = (float*)d_out;                // (512,)

    char* ws = (char*)d_ws;
    float*          Mt  = (float*)(ws + 0);                  // 640*512*4   = 1310720
    float*          obH = (float*)(ws + 1310720);            // 2*512*128*4 =  524288
    unsigned short* h1b = (unsigned short*)(ws + 1835008);   // 512*512*2   =  524288
    unsigned short* h2b = (unsigned short*)(ws + 2359296);   // 512*256*2   =  262144
    // total 2,621,440 bytes

    // 1) h1 = lrelu(x @ W1 + b1)  (512x512, K=1024) -> bf16
    gemm_k<8, 128, M_F32ROW, M_F32COL, true, true, true, false>
        <<<dim3(H1_ / 32, B_ / 32), 512, 0, stream>>>(
        x, W1, b1, h1b, B_, H1_, F_, H1_);

    // 2) h2 = lrelu(h1 @ W2 + b2) (512x256, K=512) -> bf16
    gemm_k<8, 64, M_BF16ROW, M_F32COL, true, true, true, false>
        <<<dim3(H2_ / 32, B_ / 32), 512, 0, stream>>>(
        h1b, W2, b2, h2b, B_, H2_, H1_, H2_);

    // 3) Mt = log2(e) * (h2 @ T)^T : A = T columns (fp32 gather, ld 640),
    //    B = h2b rows (bf16) -> Mt fp32 [640][512], pre-scaled for exp2
    gemm_k<4, 64, M_F32COL, M_BF16ROW, false, false, false, true>
        <<<dim3(B_ / 32, NT_ / 32), 256, 0, stream>>>(
        T, h2b, nullptr, Mt, NT_, B_, NT_, H2_);

    // 4) minibatch discrimination -> obH (two i-half partials)
    disc_kernel<<<1024, 128, 0, stream>>>(Mt, obH);

    // 5) out = (lrelu(concat([h2, ob]) @ W3 + b3)) @ W4 + b4
    gemm3_dot<<<B_ / 32, 256, 0, stream>>>(
        h2b, obH, obH + B_ * OUT_, W3, b3, W4, b4, out);
}